// Round 7
// baseline (1172.935 us; speedup 1.0000x reference)
//
#include <hip/hip_runtime.h>
#include <stdint.h>

// ContextAttention: B=4, S=4096, D=512.
// Round 7: proj_mfma (unchanged) + attn_split (Tq=128, kv-split across 2
// blocks, K+V LDS-staged with XOR swizzle, shfl-based P transform, no Ps
// round-trip) + merge kernel. Fallback to round-6 attn_mfma if ws too small.
// NOTE: __launch_bounds__ is BANNED (crashed rounds 1-3).

#define BDIM 4
#define SDIM 4096
#define DDIM 512
#define MROWS (BDIM * SDIM)  // 16384

typedef short short8_t __attribute__((ext_vector_type(8)));
typedef short short4_t __attribute__((ext_vector_type(4)));
typedef float float4_t __attribute__((ext_vector_type(4)));

__device__ __forceinline__ short f2bf(float f) {
    union { float f; uint32_t u; } v; v.f = f;
    uint32_t r = v.u + 0x7FFFu + ((v.u >> 16) & 1u);  // RNE
    return (short)(r >> 16);
}
__device__ __forceinline__ float bf2f(short s) {
    union { uint32_t u; float f; } v; v.u = ((uint32_t)(uint16_t)s) << 16;
    return v.f;
}

// Storage-dtype vote (unchanged).
__global__ void detect_kernel(const uint32_t* __restrict__ tok, int* __restrict__ flag) {
    __shared__ int red[256];
    const int tid = threadIdx.x;
    int c = 0;
    for (int i = tid; i < 4096; i += 256) {
        uint32_t e = (tok[i] >> 7) & 0xFFu;
        c += (e >= 105u && e <= 135u) ? 1 : 0;
    }
    red[tid] = c;
    __syncthreads();
    for (int s = 128; s > 0; s >>= 1) {
        if (tid < s) red[tid] += red[tid + s];
        __syncthreads();
    }
    if (tid == 0) *flag = (red[0] > 2048) ? 1 : 0;  // 1 = bf16 storage
}

// ---------------- MFMA projection (unchanged from round 6) ----------------
__global__ void proj_mfma(const void* __restrict__ X, const void* __restrict__ W1,
                          const void* __restrict__ W2, const void* __restrict__ W3,
                          short* __restrict__ QKV, const int* __restrict__ flagp)
{
    __shared__ __align__(16) short As[128][40];
    __shared__ __align__(16) short Bs[128][40];

    const int bf16in = *flagp;
    const int bid = blockIdx.x;
    const int g = bid >> 9;
    const int r = bid & 511;

    const void* Ap; const void* Bp; short* Op;
    int m0, n0, ldo;
    if (g == 2) {
        Ap = W3; Bp = X; Op = QKV + 2 * (size_t)MROWS * DDIM;
        m0 = 128 * (r & 3); n0 = 128 * (r >> 2); ldo = MROWS;   // Vt[e][bs]
    } else {
        Ap = X; Bp = (g == 0) ? W1 : W2; Op = QKV + (size_t)g * MROWS * DDIM;
        m0 = 128 * (r >> 2); n0 = 128 * (r & 3); ldo = DDIM;    // Q/K[bs][e]
    }

    const float* Af = (const float*)Ap;  const float* Bf = (const float*)Bp;
    const short* Ah = (const short*)Ap;  const short* Bh = (const short*)Bp;

    const int tid = threadIdx.x;
    const int w = tid >> 6, lane = tid & 63, quad = lane >> 4, l16 = lane & 15;
    const int wm = w >> 1, wn = w & 1;
    const int rgrp = tid >> 3, cg = tid & 7;

    const float4_t z4 = {0.f, 0.f, 0.f, 0.f};
    float4_t acc[4][4];
#pragma unroll
    for (int i = 0; i < 4; ++i)
#pragma unroll
        for (int j = 0; j < 4; ++j) acc[i][j] = z4;

    for (int kk = 0; kk < 16; ++kk) {
        const int k0 = 32 * kk;
        __syncthreads();
        if (bf16in) {
#pragma unroll
            for (int i = 0; i < 4; ++i) {
                const int row = rgrp + 32 * i;
                *(short4_t*)&As[row][4 * cg] =
                    *(const short4_t*)(Ah + (size_t)(m0 + row) * DDIM + k0 + 4 * cg);
                *(short4_t*)&Bs[row][4 * cg] =
                    *(const short4_t*)(Bh + (size_t)(n0 + row) * DDIM + k0 + 4 * cg);
            }
        } else {
#pragma unroll
            for (int i = 0; i < 4; ++i) {
                const int row = rgrp + 32 * i;
                float4 va = *(const float4*)(Af + (size_t)(m0 + row) * DDIM + k0 + 4 * cg);
                short4_t sa = { f2bf(va.x), f2bf(va.y), f2bf(va.z), f2bf(va.w) };
                *(short4_t*)&As[row][4 * cg] = sa;
                float4 vb = *(const float4*)(Bf + (size_t)(n0 + row) * DDIM + k0 + 4 * cg);
                short4_t sb = { f2bf(vb.x), f2bf(vb.y), f2bf(vb.z), f2bf(vb.w) };
                *(short4_t*)&Bs[row][4 * cg] = sb;
            }
        }
        __syncthreads();

        short8_t af[4], bfr[4];
#pragma unroll
        for (int mt = 0; mt < 4; ++mt)
            af[mt] = *(const short8_t*)&As[64 * wm + 16 * mt + l16][8 * quad];
#pragma unroll
        for (int nt = 0; nt < 4; ++nt)
            bfr[nt] = *(const short8_t*)&Bs[64 * wn + 16 * nt + l16][8 * quad];
#pragma unroll
        for (int mt = 0; mt < 4; ++mt)
#pragma unroll
            for (int nt = 0; nt < 4; ++nt)
                acc[mt][nt] = __builtin_amdgcn_mfma_f32_16x16x32_bf16(af[mt], bfr[nt], acc[mt][nt], 0, 0, 0);
    }

#pragma unroll
    for (int mt = 0; mt < 4; ++mt)
#pragma unroll
        for (int nt = 0; nt < 4; ++nt)
#pragma unroll
            for (int rr = 0; rr < 4; ++rr) {
                const int m = m0 + 64 * wm + 16 * mt + 4 * quad + rr;
                const int n = n0 + 64 * wn + 16 * nt + l16;
                Op[(size_t)m * ldo + n] = f2bf(acc[mt][nt][rr]);
            }
}

// ---------------- attn_split: flash attention, kv-split ----------------
// Grid 256 x 512 threads. bid: kvh = bid&1 (kv half, 2048 rows), qt =
// (bid>>1)&31 (q-tile of 128), b = bid>>6. Wave w owns q rows q0+16w..+16.
// Per iter (Tk=32): stage K-tile[32][512] + V-tile[512][32] in swizzled LDS;
// S^T = K @ Q^T (A=K-frag m=kv, B=qf n=q); exp+pack in regs; shfl-transform
// C/D -> PV A-frag; PV over full D (32 MFMA), acc 128 VGPR. Wave-independent
// between barriers. Writes UNNORMALIZED partial O (fp32) + partial rowsums.
__global__ void attn_split(const short* __restrict__ QKV,
                           float* __restrict__ Opart, float* __restrict__ RS)
{
    __shared__ __align__(16) short Ksm[32 * 512];  // [kv][d], 16B-chunk XOR swizzle
    __shared__ __align__(16) short Vsm[512 * 32];  // [d][kv], 16B-chunk XOR swizzle

    const short* Qb = QKV;
    const short* Kb = QKV + (size_t)MROWS * DDIM;
    const short* Vt = QKV + 2 * (size_t)MROWS * DDIM;  // [512][16384]

    const int bid = blockIdx.x;
    const int kvh = bid & 1;
    const int qt = (bid >> 1) & 31;
    const int b = bid >> 6;
    const int q0 = 128 * qt;

    const int tid = threadIdx.x;
    const int w = tid >> 6, lane = tid & 63, quad = lane >> 4, l16 = lane & 15;

    // Persistent Q B-frags: n=l16 (q row q0+16w+l16), k=8*quad+j (d)
    short8_t qf[16];
    {
        const short* qrow = Qb + (size_t)(b * SDIM + q0 + 16 * w + l16) * DDIM + 8 * quad;
#pragma unroll
        for (int kc = 0; kc < 16; ++kc)
            qf[kc] = *(const short8_t*)(qrow + 32 * kc);
    }

    const float4_t z4 = {0.f, 0.f, 0.f, 0.f};
    float4_t acc[32];
#pragma unroll
    for (int nt = 0; nt < 32; ++nt) acc[nt] = z4;
    float rs = 0.f;

    const float kSc = 1.44269504088896341f * 0.04419417382415922f;  // log2(e)/sqrt(512)
    const int sel = quad & 1;          // for transform
    const int tt = (quad >> 1) & 1;
    const int s0 = 32 * sel + l16, s1 = s0 + 16;

    for (int kt = 0; kt < 64; ++kt) {
        const int kvbase = 2048 * kvh + 32 * kt;
        __syncthreads();  // prior iter's LDS reads done

        // Stage K rows: wave w -> kv 4w..4w+3. Lane covers 16B chunk `lane`,
        // stored at physical chunk lane ^ (kv&7).
#pragma unroll
        for (int r = 0; r < 4; ++r) {
            const int kv = 4 * w + r;
            short8_t t = *(const short8_t*)(Kb + (size_t)(b * SDIM + kvbase + kv) * DDIM + 8 * lane);
            *(short8_t*)&Ksm[kv * 512 + ((lane ^ (kv & 7)) << 3)] = t;
        }
        // Stage V rows: wave w -> d 64w..64w+63; 4 lanes per 64B row.
#pragma unroll
        for (int i = 0; i < 4; ++i) {
            const int d = 64 * w + 16 * i + (lane >> 2);
            const int c = lane & 3;
            short8_t t = *(const short8_t*)(Vt + (size_t)d * MROWS + b * SDIM + kvbase + 8 * c);
            *(short8_t*)&Vsm[d * 32 + ((c ^ (d & 3)) << 3)] = t;
        }
        __syncthreads();  // tiles ready

        // S^T tiles: T_t[kv=16t+4*quad+r][q=l16], A=K-frag (m=kv), B=qf.
        float4_t T0 = z4, T1 = z4;
#pragma unroll
        for (int kc = 0; kc < 16; ++kc) {
            const int pc = ((4 * kc + quad) ^ (l16 & 7)) << 3;
            short8_t k0 = *(const short8_t*)&Ksm[l16 * 512 + pc];
            short8_t k1 = *(const short8_t*)&Ksm[(16 + l16) * 512 + pc];
            T0 = __builtin_amdgcn_mfma_f32_16x16x32_bf16(k0, qf[kc], T0, 0, 0, 0);
            T1 = __builtin_amdgcn_mfma_f32_16x16x32_bf16(k1, qf[kc], T1, 0, 0, 0);
        }

        // exp (fp32), pack bf16 pairs; rowsum from rounded P (lane's q = l16).
        int pr[2][2];
#pragma unroll
        for (int t = 0; t < 2; ++t) {
            const float4_t& T = t ? T1 : T0;
#pragma unroll
            for (int m = 0; m < 2; ++m) {
                const float p0 = exp2f(T[2 * m] * kSc);
                const float p1 = exp2f(T[2 * m + 1] * kSc);
                const short u0 = f2bf(p0), u1 = f2bf(p1);
                rs += bf2f(u0) + bf2f(u1);
                pr[t][m] = ((int)(uint16_t)u1 << 16) | (uint16_t)u0;
            }
        }

        // Transform C/D -> PV A-frag (m=q=l16, k=kv=8*quad+j):
        // w_n = pr[t=quad>>1][n&1] from src lane 32*(quad&1) + 16*(n>>1) + l16.
        union { int wi[4]; short8_t s8; } pa;
        {
            int a, bb;
            a = __shfl(pr[0][0], s0); bb = __shfl(pr[1][0], s0); pa.wi[0] = tt ? bb : a;
            a = __shfl(pr[0][1], s0); bb = __shfl(pr[1][1], s0); pa.wi[1] = tt ? bb : a;
            a = __shfl(pr[0][0], s1); bb = __shfl(pr[1][0], s1); pa.wi[2] = tt ? bb : a;
            a = __shfl(pr[0][1], s1); bb = __shfl(pr[1][1], s1); pa.wi[3] = tt ? bb : a;
        }

        // PV: acc[nt] += P[16q x 32kv] @ V[32kv x 16d], B-frag n=d=16nt+l16.
#pragma unroll
        for (int nt = 0; nt < 32; ++nt) {
            const int d = 16 * nt + l16;
            short8_t vb = *(const short8_t*)&Vsm[d * 32 + ((quad ^ (l16 & 3)) << 3)];
            acc[nt] = __builtin_amdgcn_mfma_f32_16x16x32_bf16(pa.s8, vb, acc[nt], 0, 0, 0);
        }
    }

    // Rowsum: lane's partial is for q=l16; reduce across quads.
    rs += __shfl_xor(rs, 16);
    rs += __shfl_xor(rs, 32);
    if (lane < 16)
        RS[(size_t)kvh * MROWS + b * SDIM + q0 + 16 * w + lane] = rs;

    // Unnormalized partial O: C/D row q = 4*quad+r, col d = 16nt+l16.
    float* Ob = Opart + (size_t)kvh * MROWS * DDIM;
#pragma unroll
    for (int nt = 0; nt < 32; ++nt) {
#pragma unroll
        for (int r = 0; r < 4; ++r)
            Ob[(size_t)(b * SDIM + q0 + 16 * w + 4 * quad + r) * DDIM + 16 * nt + l16] = acc[nt][r];
    }
}

// Merge: out[q][d] = (O0+O1)/(rs0+rs1), dtype per flag.
__global__ void merge_kernel(const float* __restrict__ Opart, const float* __restrict__ RS,
                             void* __restrict__ out, const int* __restrict__ flagp)
{
    const int bf16out = *flagp;
    const int q = blockIdx.x;
    const int tid = threadIdx.x;
    const float inv = 1.0f / (RS[q] + RS[MROWS + q]);
    const float* O0 = Opart + (size_t)q * DDIM;
    const float* O1 = Opart + (size_t)MROWS * DDIM + (size_t)q * DDIM;
    for (int d = tid; d < DDIM; d += 256) {
        const float o = (O0[d] + O1[d]) * inv;
        if (bf16out) ((short*)out)[(size_t)q * DDIM + d] = f2bf(o);
        else         ((float*)out)[(size_t)q * DDIM + d] = o;
    }
}

// ---------------- Fallback attn (round 6, proven) ----------------
__global__ void attn_mfma(const short* __restrict__ QKV, void* __restrict__ out,
                          const int* __restrict__ flagp)
{
    __shared__ __align__(16) short Ks[32][520];
    __shared__ __align__(16) short Ps[32][72];
    __shared__ float rowsum[2][32];

    const int bf16out = *flagp;
    const short* Qb = QKV;
    const short* Kb = QKV + (size_t)MROWS * DDIM;
    const short* Vt = QKV + 2 * (size_t)MROWS * DDIM;

    const int b = blockIdx.x >> 7;
    const int q0 = (blockIdx.x & 127) * 32;
    const int tid = threadIdx.x;
    const int w = tid >> 6, lane = tid & 63, quad = lane >> 4, l16 = lane & 15;
    const int strip = w >> 1, half = w & 1;

    short8_t qf[16];
    {
        const short* qrow = Qb + (size_t)(b * SDIM + q0 + 16 * strip + l16) * DDIM + 8 * quad;
#pragma unroll
        for (int kc = 0; kc < 16; ++kc)
            qf[kc] = *(const short8_t*)(qrow + 32 * kc);
    }

    const float4_t z4 = {0.f, 0.f, 0.f, 0.f};
    float4_t o[2][8];
#pragma unroll
    for (int mt = 0; mt < 2; ++mt)
#pragma unroll
        for (int nt = 0; nt < 8; ++nt) o[mt][nt] = z4;
    float rs[4] = {0.f, 0.f, 0.f, 0.f};

    const float kSc = 1.44269504088896341f * 0.04419417382415922f;

    for (int kt = 0; kt < 128; ++kt) {
        const int kv0 = 32 * kt;
        __syncthreads();
#pragma unroll
        for (int r = 0; r < 8; ++r) {
            const int kv = 8 * w + r;
            short8_t t = *(const short8_t*)(Kb + (size_t)(b * SDIM + kv0 + kv) * DDIM + 8 * lane);
            *(short8_t*)&Ks[kv][8 * lane] = t;
        }
        __syncthreads();

        float4_t sacc = z4;
#pragma unroll
        for (int kc = 0; kc < 16; ++kc) {
            short8_t kf = *(const short8_t*)&Ks[16 * half + l16][32 * kc + 8 * quad];
            sacc = __builtin_amdgcn_mfma_f32_16x16x32_bf16(qf[kc], kf, sacc, 0, 0, 0);
        }

#pragma unroll
        for (int r = 0; r < 4; ++r) {
            const float p = exp2f(sacc[r] * kSc);
            const short pb = f2bf(p);
            rs[r] += bf2f(pb);
            Ps[16 * strip + 4 * quad + r][16 * half + l16] = pb;
        }
        __syncthreads();

        short8_t pa0 = *(const short8_t*)&Ps[l16][8 * quad];
        short8_t pa1 = *(const short8_t*)&Ps[16 + l16][8 * quad];
#pragma unroll
        for (int nt = 0; nt < 8; ++nt) {
            const short* vp = Vt + (size_t)(128 * w + 16 * nt + l16) * MROWS
                            + (b * SDIM + kv0 + 8 * quad);
            short8_t vb = *(const short8_t*)vp;
            o[0][nt] = __builtin_amdgcn_mfma_f32_16x16x32_bf16(pa0, vb, o[0][nt], 0, 0, 0);
            o[1][nt] = __builtin_amdgcn_mfma_f32_16x16x32_bf16(pa1, vb, o[1][nt], 0, 0, 0);
        }
    }

#pragma unroll
    for (int r = 0; r < 4; ++r) {
        float v = rs[r];
        v += __shfl_xor(v, 1); v += __shfl_xor(v, 2);
        v += __shfl_xor(v, 4); v += __shfl_xor(v, 8);
        rs[r] = v;
    }
    if (l16 == 0) {
#pragma unroll
        for (int r = 0; r < 4; ++r)
            rowsum[half][16 * strip + 4 * quad + r] = rs[r];
    }
    __syncthreads();

#pragma unroll
    for (int mt = 0; mt < 2; ++mt)
#pragma unroll
        for (int r = 0; r < 4; ++r) {
            const int q = 16 * mt + 4 * quad + r;
            const float inv = 1.0f / (rowsum[0][q] + rowsum[1][q]);
            const size_t base = (size_t)(b * SDIM + q0 + q) * DDIM + 128 * w + l16;
            if (bf16out) {
                short* orow = (short*)out + base;
#pragma unroll
                for (int nt = 0; nt < 8; ++nt)
                    orow[16 * nt] = f2bf(o[mt][nt][r] * inv);
            } else {
                float* orow = (float*)out + base;
#pragma unroll
                for (int nt = 0; nt < 8; ++nt)
                    orow[16 * nt] = o[mt][nt][r] * inv;
            }
        }
}

__global__ void zero_out_kernel(short* __restrict__ out, int n) {
    int i = blockIdx.x * 256 + threadIdx.x;
    if (i < n) out[i] = 0;
}

extern "C" void kernel_launch(void* const* d_in, const int* in_sizes, int n_in,
                              void* d_out, int out_size, void* d_ws, size_t ws_size,
                              hipStream_t stream) {
    const void* token = d_in[0];
    const void* Wp[3] = { d_in[1], d_in[2], d_in[3] };
    {
        int wi = 0;
        const void* tk = nullptr; const void* ws3[3] = {nullptr, nullptr, nullptr};
        bool ok = true;
        for (int i = 0; i < n_in && i < 4; ++i) {
            if (in_sizes[i] == BDIM * SDIM * DDIM) { if (tk) ok = false; tk = d_in[i]; }
            else if (in_sizes[i] == DDIM * DDIM) { if (wi < 3) ws3[wi++] = d_in[i]; else ok = false; }
            else ok = false;
        }
        if (ok && tk && wi == 3) { token = tk; Wp[0] = ws3[0]; Wp[1] = ws3[1]; Wp[2] = ws3[2]; }
    }

    const size_t qkvBytes = 3 * (size_t)MROWS * DDIM * sizeof(short);  // 48 MB
    const size_t need_base = qkvBytes + 256;
    if (ws_size < need_base) {
        zero_out_kernel<<<(out_size + 255) / 256, 256, 0, stream>>>((short*)d_out, out_size);
        return;
    }

    short* QKV = (short*)d_ws;
    int* flag = (int*)((char*)d_ws + qkvBytes);           // 256B slot at +48MB
    float* Opart = (float*)((char*)d_ws + need_base);     // 2 x 16384 x 512 fp32 = 64MB
    float* RS = Opart + 2 * (size_t)MROWS * DDIM;         // 2 x 16384 fp32 = 128KB
    const size_t need_split = need_base
        + 2 * (size_t)MROWS * DDIM * sizeof(float)
        + 2 * (size_t)MROWS * sizeof(float);

    detect_kernel<<<1, 256, 0, stream>>>((const uint32_t*)token, flag);
    proj_mfma<<<dim3(1536), 256, 0, stream>>>(token, Wp[0], Wp[1], Wp[2], QKV, flag);

    if (ws_size >= need_split) {
        attn_split<<<dim3(256), 512, 0, stream>>>(QKV, Opart, RS);
        merge_kernel<<<dim3(MROWS), 256, 0, stream>>>(Opart, RS, d_out, flag);
    } else {
        attn_mfma<<<dim3(512), 256, 0, stream>>>(QKV, d_out, flag);
    }
}

// Round 8
// 486.305 us; speedup vs baseline: 2.4119x; 2.4119x over previous
//
#include <hip/hip_runtime.h>
#include <stdint.h>

// ContextAttention: B=4, S=4096, D=512.
// Round 8: attention as two materialized-P GEMMs (both clones of the proven
// proj_mfma register shape: 64 arch VGPR + 64 AGPR, no spill):
//   qkt: P = exp(Q K^T * sc) (bf16, unnormalized) + rowsums RS (atomicAdd)
//   pv : out = (P @ V^T-rows) / RS
// Round 7's fused attn_split hit compiler default-budget scratch spill
// (VGPR_Count=64, 3.2 GB HBM/dispatch) -> abandoned.
// BANNED: __launch_bounds__ (crash-assoc rounds 1-3). All grids 1-D.

#define BDIM 4
#define SDIM 4096
#define DDIM 512
#define MROWS (BDIM * SDIM)  // 16384

typedef short short8_t __attribute__((ext_vector_type(8)));
typedef short short4_t __attribute__((ext_vector_type(4)));
typedef float float4_t __attribute__((ext_vector_type(4)));

__device__ __forceinline__ short f2bf(float f) {
    union { float f; uint32_t u; } v; v.f = f;
    uint32_t r = v.u + 0x7FFFu + ((v.u >> 16) & 1u);  // RNE
    return (short)(r >> 16);
}
__device__ __forceinline__ float bf2f(short s) {
    union { uint32_t u; float f; } v; v.u = ((uint32_t)(uint16_t)s) << 16;
    return v.f;
}

// Storage-dtype vote (proven).
__global__ void detect_kernel(const uint32_t* __restrict__ tok, int* __restrict__ flag) {
    __shared__ int red[256];
    const int tid = threadIdx.x;
    int c = 0;
    for (int i = tid; i < 4096; i += 256) {
        uint32_t e = (tok[i] >> 7) & 0xFFu;
        c += (e >= 105u && e <= 135u) ? 1 : 0;
    }
    red[tid] = c;
    __syncthreads();
    for (int s = 128; s > 0; s >>= 1) {
        if (tid < s) red[tid] += red[tid + s];
        __syncthreads();
    }
    if (tid == 0) *flag = (red[0] > 2048) ? 1 : 0;  // 1 = bf16 storage
}

__global__ void zero_rs_kernel(float* __restrict__ RS) {
    RS[blockIdx.x * 256 + threadIdx.x] = 0.f;
}

// ---------------- MFMA projection (unchanged, proven) ----------------
__global__ void proj_mfma(const void* __restrict__ X, const void* __restrict__ W1,
                          const void* __restrict__ W2, const void* __restrict__ W3,
                          short* __restrict__ QKV, const int* __restrict__ flagp)
{
    __shared__ __align__(16) short As[128][40];
    __shared__ __align__(16) short Bs[128][40];

    const int bf16in = *flagp;
    const int bid = blockIdx.x;
    const int g = bid >> 9;
    const int r = bid & 511;

    const void* Ap; const void* Bp; short* Op;
    int m0, n0, ldo;
    if (g == 2) {
        Ap = W3; Bp = X; Op = QKV + 2 * (size_t)MROWS * DDIM;
        m0 = 128 * (r & 3); n0 = 128 * (r >> 2); ldo = MROWS;   // Vt[e][bs]
    } else {
        Ap = X; Bp = (g == 0) ? W1 : W2; Op = QKV + (size_t)g * MROWS * DDIM;
        m0 = 128 * (r >> 2); n0 = 128 * (r & 3); ldo = DDIM;    // Q/K[bs][e]
    }

    const float* Af = (const float*)Ap;  const float* Bf = (const float*)Bp;
    const short* Ah = (const short*)Ap;  const short* Bh = (const short*)Bp;

    const int tid = threadIdx.x;
    const int w = tid >> 6, lane = tid & 63, quad = lane >> 4, l16 = lane & 15;
    const int wm = w >> 1, wn = w & 1;
    const int rgrp = tid >> 3, cg = tid & 7;

    const float4_t z4 = {0.f, 0.f, 0.f, 0.f};
    float4_t acc[4][4];
#pragma unroll
    for (int i = 0; i < 4; ++i)
#pragma unroll
        for (int j = 0; j < 4; ++j) acc[i][j] = z4;

    for (int kk = 0; kk < 16; ++kk) {
        const int k0 = 32 * kk;
        __syncthreads();
        if (bf16in) {
#pragma unroll
            for (int i = 0; i < 4; ++i) {
                const int row = rgrp + 32 * i;
                *(short4_t*)&As[row][4 * cg] =
                    *(const short4_t*)(Ah + (size_t)(m0 + row) * DDIM + k0 + 4 * cg);
                *(short4_t*)&Bs[row][4 * cg] =
                    *(const short4_t*)(Bh + (size_t)(n0 + row) * DDIM + k0 + 4 * cg);
            }
        } else {
#pragma unroll
            for (int i = 0; i < 4; ++i) {
                const int row = rgrp + 32 * i;
                float4 va = *(const float4*)(Af + (size_t)(m0 + row) * DDIM + k0 + 4 * cg);
                short4_t sa = { f2bf(va.x), f2bf(va.y), f2bf(va.z), f2bf(va.w) };
                *(short4_t*)&As[row][4 * cg] = sa;
                float4 vb = *(const float4*)(Bf + (size_t)(n0 + row) * DDIM + k0 + 4 * cg);
                short4_t sb = { f2bf(vb.x), f2bf(vb.y), f2bf(vb.z), f2bf(vb.w) };
                *(short4_t*)&Bs[row][4 * cg] = sb;
            }
        }
        __syncthreads();

        short8_t af[4], bfr[4];
#pragma unroll
        for (int mt = 0; mt < 4; ++mt)
            af[mt] = *(const short8_t*)&As[64 * wm + 16 * mt + l16][8 * quad];
#pragma unroll
        for (int nt = 0; nt < 4; ++nt)
            bfr[nt] = *(const short8_t*)&Bs[64 * wn + 16 * nt + l16][8 * quad];
#pragma unroll
        for (int mt = 0; mt < 4; ++mt)
#pragma unroll
            for (int nt = 0; nt < 4; ++nt)
                acc[mt][nt] = __builtin_amdgcn_mfma_f32_16x16x32_bf16(af[mt], bfr[nt], acc[mt][nt], 0, 0, 0);
    }

#pragma unroll
    for (int mt = 0; mt < 4; ++mt)
#pragma unroll
        for (int nt = 0; nt < 4; ++nt)
#pragma unroll
            for (int rr = 0; rr < 4; ++rr) {
                const int m = m0 + 64 * wm + 16 * mt + 4 * quad + rr;
                const int n = n0 + 64 * wn + 16 * nt + l16;
                Op[(size_t)m * ldo + n] = f2bf(acc[mt][nt][rr]);
            }
}

// ---------------- qkt: P = exp(sc * Q K^T) + rowsums ----------------
// Grid nb*1024 blocks: bb = bid>>10 (local batch), tile r = bid&1023:
// m0 = 128*(r>>5) q-rows, n0 = 128*(r&31) kv-cols. K-loop over D=512.
__global__ void qkt_kernel(const short* __restrict__ QKV, short* __restrict__ P,
                           float* __restrict__ RS, int bbase)
{
    __shared__ __align__(16) short As[128][40];
    __shared__ __align__(16) short Bs[128][40];

    const short* Qb = QKV;
    const short* Kb = QKV + (size_t)MROWS * DDIM;

    const int bid = blockIdx.x;
    const int bb = bid >> 10;
    const int r = bid & 1023;
    const int b = bbase + bb;
    const int m0 = 128 * (r >> 5);
    const int n0 = 128 * (r & 31);

    const int tid = threadIdx.x;
    const int w = tid >> 6, lane = tid & 63, quad = lane >> 4, l16 = lane & 15;
    const int wm = w >> 1, wn = w & 1;
    const int rgrp = tid >> 3, cg = tid & 7;

    const float4_t z4 = {0.f, 0.f, 0.f, 0.f};
    float4_t acc[4][4];
#pragma unroll
    for (int i = 0; i < 4; ++i)
#pragma unroll
        for (int j = 0; j < 4; ++j) acc[i][j] = z4;

    for (int kk = 0; kk < 16; ++kk) {
        const int k0 = 32 * kk;
        __syncthreads();
#pragma unroll
        for (int i = 0; i < 4; ++i) {
            const int row = rgrp + 32 * i;
            *(short4_t*)&As[row][4 * cg] =
                *(const short4_t*)(Qb + (size_t)(b * SDIM + m0 + row) * DDIM + k0 + 4 * cg);
            *(short4_t*)&Bs[row][4 * cg] =
                *(const short4_t*)(Kb + (size_t)(b * SDIM + n0 + row) * DDIM + k0 + 4 * cg);
        }
        __syncthreads();

        short8_t af[4], bfr[4];
#pragma unroll
        for (int mt = 0; mt < 4; ++mt)
            af[mt] = *(const short8_t*)&As[64 * wm + 16 * mt + l16][8 * quad];
#pragma unroll
        for (int nt = 0; nt < 4; ++nt)
            bfr[nt] = *(const short8_t*)&Bs[64 * wn + 16 * nt + l16][8 * quad];
#pragma unroll
        for (int mt = 0; mt < 4; ++mt)
#pragma unroll
            for (int nt = 0; nt < 4; ++nt)
                acc[mt][nt] = __builtin_amdgcn_mfma_f32_16x16x32_bf16(af[mt], bfr[nt], acc[mt][nt], 0, 0, 0);
    }

    // Epilogue: exp -> bf16 P (unnormalized), per-row partial sums -> RS.
    const float kSc = 1.44269504088896341f * 0.04419417382415922f;  // log2(e)/sqrt(512)
    short* Pb = P + (size_t)bb * SDIM * SDIM;
#pragma unroll
    for (int mt = 0; mt < 4; ++mt)
#pragma unroll
        for (int rr = 0; rr < 4; ++rr) {
            const int q = m0 + 64 * wm + 16 * mt + 4 * quad + rr;
            float sum = 0.f;
#pragma unroll
            for (int nt = 0; nt < 4; ++nt) {
                const float p = exp2f(acc[mt][nt][rr] * kSc);
                const short pb = f2bf(p);
                sum += bf2f(pb);
                Pb[(size_t)q * SDIM + n0 + 64 * wn + 16 * nt + l16] = pb;
            }
            sum += __shfl_xor(sum, 1); sum += __shfl_xor(sum, 2);
            sum += __shfl_xor(sum, 4); sum += __shfl_xor(sum, 8);
            if (l16 == 0) atomicAdd(&RS[(size_t)b * SDIM + q], sum);
        }
}

// ---------------- pv: out = (P @ Vt-rows) / RS ----------------
// Grid nb*128: bb = bid>>7, tile r = bid&127: m0 = 128*(r>>2), n0 = 128*(r&3).
// K-loop over kv=4096 (128 iters). A = P[q][kv] (bf16), B = Vt[d][kv].
__global__ void pv_kernel(const short* __restrict__ P, const short* __restrict__ QKV,
                          const float* __restrict__ RS, void* __restrict__ out,
                          const int* __restrict__ flagp, int bbase)
{
    __shared__ __align__(16) short As[128][40];
    __shared__ __align__(16) short Bs[128][40];

    const int bf16out = *flagp;
    const short* Vt = QKV + 2 * (size_t)MROWS * DDIM;  // [512][16384]

    const int bid = blockIdx.x;
    const int bb = bid >> 7;
    const int r = bid & 127;
    const int b = bbase + bb;
    const int m0 = 128 * (r >> 2);
    const int n0 = 128 * (r & 3);

    const int tid = threadIdx.x;
    const int w = tid >> 6, lane = tid & 63, quad = lane >> 4, l16 = lane & 15;
    const int wm = w >> 1, wn = w & 1;
    const int rgrp = tid >> 3, cg = tid & 7;

    const short* Pb = P + (size_t)bb * SDIM * SDIM;

    const float4_t z4 = {0.f, 0.f, 0.f, 0.f};
    float4_t acc[4][4];
#pragma unroll
    for (int i = 0; i < 4; ++i)
#pragma unroll
        for (int j = 0; j < 4; ++j) acc[i][j] = z4;

    for (int kk = 0; kk < 128; ++kk) {
        const int k0 = 32 * kk;
        __syncthreads();
#pragma unroll
        for (int i = 0; i < 4; ++i) {
            const int row = rgrp + 32 * i;
            *(short4_t*)&As[row][4 * cg] =
                *(const short4_t*)(Pb + (size_t)(m0 + row) * SDIM + k0 + 4 * cg);
            *(short4_t*)&Bs[row][4 * cg] =
                *(const short4_t*)(Vt + (size_t)(n0 + row) * MROWS + b * SDIM + k0 + 4 * cg);
        }
        __syncthreads();

        short8_t af[4], bfr[4];
#pragma unroll
        for (int mt = 0; mt < 4; ++mt)
            af[mt] = *(const short8_t*)&As[64 * wm + 16 * mt + l16][8 * quad];
#pragma unroll
        for (int nt = 0; nt < 4; ++nt)
            bfr[nt] = *(const short8_t*)&Bs[64 * wn + 16 * nt + l16][8 * quad];
#pragma unroll
        for (int mt = 0; mt < 4; ++mt)
#pragma unroll
            for (int nt = 0; nt < 4; ++nt)
                acc[mt][nt] = __builtin_amdgcn_mfma_f32_16x16x32_bf16(af[mt], bfr[nt], acc[mt][nt], 0, 0, 0);
    }

    // Epilogue: divide by softmax denominator, write out (dtype per flag).
#pragma unroll
    for (int mt = 0; mt < 4; ++mt)
#pragma unroll
        for (int rr = 0; rr < 4; ++rr) {
            const size_t grow = (size_t)b * SDIM + m0 + 64 * wm + 16 * mt + 4 * quad + rr;
            const float inv = 1.0f / RS[grow];
#pragma unroll
            for (int nt = 0; nt < 4; ++nt) {
                const int n = n0 + 64 * wn + 16 * nt + l16;
                const float o = acc[mt][nt][rr] * inv;
                if (bf16out) ((short*)out)[grow * DDIM + n] = f2bf(o);
                else         ((float*)out)[grow * DDIM + n] = o;
            }
        }
}

// ---------------- Fallback attn (round 6, proven) ----------------
__global__ void attn_mfma(const short* __restrict__ QKV, void* __restrict__ out,
                          const int* __restrict__ flagp)
{
    __shared__ __align__(16) short Ks[32][520];
    __shared__ __align__(16) short Ps[32][72];
    __shared__ float rowsum[2][32];

    const int bf16out = *flagp;
    const short* Qb = QKV;
    const short* Kb = QKV + (size_t)MROWS * DDIM;
    const short* Vt = QKV + 2 * (size_t)MROWS * DDIM;

    const int b = blockIdx.x >> 7;
    const int q0 = (blockIdx.x & 127) * 32;
    const int tid = threadIdx.x;
    const int w = tid >> 6, lane = tid & 63, quad = lane >> 4, l16 = lane & 15;
    const int strip = w >> 1, half = w & 1;

    short8_t qf[16];
    {
        const short* qrow = Qb + (size_t)(b * SDIM + q0 + 16 * strip + l16) * DDIM + 8 * quad;
#pragma unroll
        for (int kc = 0; kc < 16; ++kc)
            qf[kc] = *(const short8_t*)(qrow + 32 * kc);
    }

    const float4_t z4 = {0.f, 0.f, 0.f, 0.f};
    float4_t o[2][8];
#pragma unroll
    for (int mt = 0; mt < 2; ++mt)
#pragma unroll
        for (int nt = 0; nt < 8; ++nt) o[mt][nt] = z4;
    float rs[4] = {0.f, 0.f, 0.f, 0.f};

    const float kSc = 1.44269504088896341f * 0.04419417382415922f;

    for (int kt = 0; kt < 128; ++kt) {
        const int kv0 = 32 * kt;
        __syncthreads();
#pragma unroll
        for (int r = 0; r < 8; ++r) {
            const int kv = 8 * w + r;
            short8_t t = *(const short8_t*)(Kb + (size_t)(b * SDIM + kv0 + kv) * DDIM + 8 * lane);
            *(short8_t*)&Ks[kv][8 * lane] = t;
        }
        __syncthreads();

        float4_t sacc = z4;
#pragma unroll
        for (int kc = 0; kc < 16; ++kc) {
            short8_t kf = *(const short8_t*)&Ks[16 * half + l16][32 * kc + 8 * quad];
            sacc = __builtin_amdgcn_mfma_f32_16x16x32_bf16(qf[kc], kf, sacc, 0, 0, 0);
        }

#pragma unroll
        for (int r = 0; r < 4; ++r) {
            const float p = exp2f(sacc[r] * kSc);
            const short pb = f2bf(p);
            rs[r] += bf2f(pb);
            Ps[16 * strip + 4 * quad + r][16 * half + l16] = pb;
        }
        __syncthreads();

        short8_t pa0 = *(const short8_t*)&Ps[l16][8 * quad];
        short8_t pa1 = *(const short8_t*)&Ps[16 + l16][8 * quad];
#pragma unroll
        for (int nt = 0; nt < 8; ++nt) {
            const short* vp = Vt + (size_t)(128 * w + 16 * nt + l16) * MROWS
                            + (b * SDIM + kv0 + 8 * quad);
            short8_t vb = *(const short8_t*)vp;
            o[0][nt] = __builtin_amdgcn_mfma_f32_16x16x32_bf16(pa0, vb, o[0][nt], 0, 0, 0);
            o[1][nt] = __builtin_amdgcn_mfma_f32_16x16x32_bf16(pa1, vb, o[1][nt], 0, 0, 0);
        }
    }

#pragma unroll
    for (int r = 0; r < 4; ++r) {
        float v = rs[r];
        v += __shfl_xor(v, 1); v += __shfl_xor(v, 2);
        v += __shfl_xor(v, 4); v += __shfl_xor(v, 8);
        rs[r] = v;
    }
    if (l16 == 0) {
#pragma unroll
        for (int r = 0; r < 4; ++r)
            rowsum[half][16 * strip + 4 * quad + r] = rs[r];
    }
    __syncthreads();

#pragma unroll
    for (int mt = 0; mt < 2; ++mt)
#pragma unroll
        for (int r = 0; r < 4; ++r) {
            const int q = 16 * mt + 4 * quad + r;
            const float inv = 1.0f / (rowsum[0][q] + rowsum[1][q]);
            const size_t base = (size_t)(b * SDIM + q0 + q) * DDIM + 128 * w + l16;
            if (bf16out) {
                short* orow = (short*)out + base;
#pragma unroll
                for (int nt = 0; nt < 8; ++nt)
                    orow[16 * nt] = f2bf(o[mt][nt][r] * inv);
            } else {
                float* orow = (float*)out + base;
#pragma unroll
                for (int nt = 0; nt < 8; ++nt)
                    orow[16 * nt] = o[mt][nt][r] * inv;
            }
        }
}

__global__ void zero_out_kernel(short* __restrict__ out, int n) {
    int i = blockIdx.x * 256 + threadIdx.x;
    if (i < n) out[i] = 0;
}

extern "C" void kernel_launch(void* const* d_in, const int* in_sizes, int n_in,
                              void* d_out, int out_size, void* d_ws, size_t ws_size,
                              hipStream_t stream) {
    const void* token = d_in[0];
    const void* Wp[3] = { d_in[1], d_in[2], d_in[3] };
    {
        int wi = 0;
        const void* tk = nullptr; const void* ws3[3] = {nullptr, nullptr, nullptr};
        bool ok = true;
        for (int i = 0; i < n_in && i < 4; ++i) {
            if (in_sizes[i] == BDIM * SDIM * DDIM) { if (tk) ok = false; tk = d_in[i]; }
            else if (in_sizes[i] == DDIM * DDIM) { if (wi < 3) ws3[wi++] = d_in[i]; else ok = false; }
            else ok = false;
        }
        if (ok && tk && wi == 3) { token = tk; Wp[0] = ws3[0]; Wp[1] = ws3[1]; Wp[2] = ws3[2]; }
    }

    const size_t qkvBytes = 3 * (size_t)MROWS * DDIM * sizeof(short);  // 48 MB
    const size_t need_base = qkvBytes + 256;
    if (ws_size < need_base) {
        zero_out_kernel<<<(out_size + 255) / 256, 256, 0, stream>>>((short*)d_out, out_size);
        return;
    }

    short* QKV = (short*)d_ws;
    int* flag = (int*)((char*)d_ws + qkvBytes);
    short* P = (short*)((char*)d_ws + need_base);
    const size_t pElems1 = (size_t)SDIM * SDIM;  // per-batch P slab

    // Pick batches-per-pass nb: need = base + nb*P + RS(64KB)
    int nb = 0;
    for (int cand = 4; cand >= 1; cand >>= 1) {
        const size_t need = need_base + (size_t)cand * pElems1 * sizeof(short)
                          + (size_t)MROWS * sizeof(float);
        if (ws_size >= need) { nb = cand; break; }
    }

    detect_kernel<<<1, 256, 0, stream>>>((const uint32_t*)token, flag);
    proj_mfma<<<dim3(1536), 256, 0, stream>>>(token, Wp[0], Wp[1], Wp[2], QKV, flag);

    if (nb == 0) {
        attn_mfma<<<dim3(512), 256, 0, stream>>>(QKV, d_out, flag);
        return;
    }

    float* RS = (float*)(P + (size_t)nb * pElems1);
    zero_rs_kernel<<<dim3(MROWS / 256), 256, 0, stream>>>(RS);
    for (int p = 0; p < BDIM / nb; ++p) {
        const int bbase = p * nb;
        qkt_kernel<<<dim3(nb * 1024), 256, 0, stream>>>(QKV, P, RS, bbase);
        pv_kernel<<<dim3(nb * 128), 256, 0, stream>>>(P, QKV, RS, d_out, flag, bbase);
    }
}

// Round 9
// 353.213 us; speedup vs baseline: 3.3208x; 1.3768x over previous
//
#include <hip/hip_runtime.h>
#include <stdint.h>

// ContextAttention: B=4, S=4096, D=512.
// Round 9: m97-style staging (global_load_lds width=16, unpadded LDS) applied
// to all three GEMMs (proj / qkt / pv). Inputs pre-converted to bf16 so every
// GEMM stages dtype-free. ws: [QKV 48MB][flag][P-slab >=32MB (Xb/Wb overlap)][RS].
// BANNED: __launch_bounds__ (crash-assoc rounds 1-3). All grids 1-D.

#define BDIM 4
#define SDIM 4096
#define DDIM 512
#define MROWS (BDIM * SDIM)  // 16384
#define XB_ELEMS ((size_t)MROWS * DDIM)        // 8388608
#define W_ELEMS ((size_t)DDIM * DDIM)          // 262144

typedef short short8_t __attribute__((ext_vector_type(8)));
typedef short short4_t __attribute__((ext_vector_type(4)));
typedef float float4_t __attribute__((ext_vector_type(4)));

typedef __attribute__((address_space(1))) void gvoid_t;
typedef __attribute__((address_space(3))) void lvoid_t;

__device__ __forceinline__ short f2bf(float f) {
    union { float f; uint32_t u; } v; v.f = f;
    uint32_t r = v.u + 0x7FFFu + ((v.u >> 16) & 1u);  // RNE
    return (short)(r >> 16);
}
__device__ __forceinline__ float bf2f(short s) {
    union { uint32_t u; float f; } v; v.u = ((uint32_t)(uint16_t)s) << 16;
    return v.f;
}

// Storage-dtype vote (proven).
__global__ void detect_kernel(const uint32_t* __restrict__ tok, int* __restrict__ flag) {
    __shared__ int red[256];
    const int tid = threadIdx.x;
    int c = 0;
    for (int i = tid; i < 4096; i += 256) {
        uint32_t e = (tok[i] >> 7) & 0xFFu;
        c += (e >= 105u && e <= 135u) ? 1 : 0;
    }
    red[tid] = c;
    __syncthreads();
    for (int s = 128; s > 0; s >>= 1) {
        if (tid < s) red[tid] += red[tid + s];
        __syncthreads();
    }
    if (tid == 0) *flag = (red[0] > 2048) ? 1 : 0;  // 1 = bf16 storage
}

__global__ void zero_rs_kernel(float* __restrict__ RS) {
    RS[blockIdx.x * 256 + threadIdx.x] = 0.f;
}

// Pre-convert inputs to bf16: dst = Xb[8388608] | W1b | W2b | W3b (262144 ea).
__global__ void convert_kernel(const void* __restrict__ X, const void* __restrict__ W1,
                               const void* __restrict__ W2, const void* __restrict__ W3,
                               short* __restrict__ dst, const int* __restrict__ flagp)
{
    const int bf16in = *flagp;
    const size_t i4 = ((size_t)blockIdx.x * 256 + threadIdx.x) * 4;  // elem index
    const void* src; size_t off;
    if (i4 < XB_ELEMS) { src = X; off = i4; }
    else {
        const size_t j = i4 - XB_ELEMS;
        const int g = (int)(j / W_ELEMS);
        src = (g == 0) ? W1 : (g == 1) ? W2 : W3;
        off = j - (size_t)g * W_ELEMS;
    }
    if (bf16in) {
        *(short4_t*)(dst + i4) = *(const short4_t*)((const short*)src + off);
    } else {
        float4 v = *(const float4*)((const float*)src + off);
        short4_t s = { f2bf(v.x), f2bf(v.y), f2bf(v.z), f2bf(v.w) };
        *(short4_t*)(dst + i4) = s;
    }
}

// ---------------- shared m97-style GEMM core ----------------
// 128x128 tile, BK=32, unpadded LDS [128][32], staged via global_load_lds
// width=16 (wave-uniform LDS base + lane*16 == row-major 16-row chunk).
__device__ __forceinline__ void gemm_core(
    const short* __restrict__ A, int lda,
    const short* __restrict__ B, int ldb,
    int m0, int n0, int kIters,
    short* As, short* Bs, float4_t acc[4][4])
{
    const int tid = threadIdx.x;
    const int w = tid >> 6, lane = tid & 63, quad = lane >> 4, l16 = lane & 15;
    const int wm = w >> 1, wn = w & 1;
    const int rsub = lane >> 2;          // row within 16-row chunk
    const int col8 = 8 * (lane & 3);     // 8-elem (16B) column chunk

    for (int kk = 0; kk < kIters; ++kk) {
        const int k0 = 32 * kk;
        __syncthreads();
#pragma unroll
        for (int c = 0; c < 2; ++c) {
            const int row = 32 * w + 16 * c + rsub;
            const short* g = A + (size_t)(m0 + row) * lda + k0 + col8;
            __builtin_amdgcn_global_load_lds((const gvoid_t*)g,
                (lvoid_t*)(As + (32 * w + 16 * c) * 32), 16, 0, 0);
        }
#pragma unroll
        for (int c = 0; c < 2; ++c) {
            const int row = 32 * w + 16 * c + rsub;
            const short* g = B + (size_t)(n0 + row) * ldb + k0 + col8;
            __builtin_amdgcn_global_load_lds((const gvoid_t*)g,
                (lvoid_t*)(Bs + (32 * w + 16 * c) * 32), 16, 0, 0);
        }
        __syncthreads();

        short8_t af[4], bfr[4];
#pragma unroll
        for (int mt = 0; mt < 4; ++mt)
            af[mt] = *(const short8_t*)&As[(64 * wm + 16 * mt + l16) * 32 + 8 * quad];
#pragma unroll
        for (int nt = 0; nt < 4; ++nt)
            bfr[nt] = *(const short8_t*)&Bs[(64 * wn + 16 * nt + l16) * 32 + 8 * quad];
#pragma unroll
        for (int mt = 0; mt < 4; ++mt)
#pragma unroll
            for (int nt = 0; nt < 4; ++nt)
                acc[mt][nt] = __builtin_amdgcn_mfma_f32_16x16x32_bf16(af[mt], bfr[nt], acc[mt][nt], 0, 0, 0);
    }
}

// ---------------- proj (all-bf16 via Xb/Wb) ----------------
// g=0: Q = Xb @ W1b^T; g=1: K; g=2: Vt[m=e][n=bs] = W3b @ Xb^T.
__global__ void proj_fast(const short* __restrict__ XbWb, short* __restrict__ QKV)
{
    __shared__ __align__(16) short As[128 * 32];
    __shared__ __align__(16) short Bs[128 * 32];

    const short* Xb = XbWb;
    const int bid = blockIdx.x;
    const int g = bid >> 9;
    const int r = bid & 511;

    const short* Ap; const short* Bp; short* Op;
    int m0, n0, ldo;
    if (g == 2) {
        Ap = XbWb + XB_ELEMS + 2 * W_ELEMS; Bp = Xb;
        Op = QKV + 2 * (size_t)MROWS * DDIM;
        m0 = 128 * (r & 3); n0 = 128 * (r >> 2); ldo = MROWS;   // Vt[e][bs]
    } else {
        Ap = Xb; Bp = XbWb + XB_ELEMS + (size_t)g * W_ELEMS;
        Op = QKV + (size_t)g * MROWS * DDIM;
        m0 = 128 * (r >> 2); n0 = 128 * (r & 3); ldo = DDIM;    // Q/K[bs][e]
    }

    const float4_t z4 = {0.f, 0.f, 0.f, 0.f};
    float4_t acc[4][4];
#pragma unroll
    for (int i = 0; i < 4; ++i)
#pragma unroll
        for (int j = 0; j < 4; ++j) acc[i][j] = z4;

    gemm_core(Ap, DDIM, Bp, DDIM, m0, n0, 16, As, Bs, acc);

    const int tid = threadIdx.x;
    const int w = tid >> 6, lane = tid & 63, quad = lane >> 4, l16 = lane & 15;
    const int wm = w >> 1, wn = w & 1;
#pragma unroll
    for (int mt = 0; mt < 4; ++mt)
#pragma unroll
        for (int nt = 0; nt < 4; ++nt)
#pragma unroll
            for (int rr = 0; rr < 4; ++rr) {
                const int m = m0 + 64 * wm + 16 * mt + 4 * quad + rr;
                const int n = n0 + 64 * wn + 16 * nt + l16;
                Op[(size_t)m * ldo + n] = f2bf(acc[mt][nt][rr]);
            }
}

// ---------------- qkt: P = exp(sc * Q K^T) + rowsums ----------------
__global__ void qkt_kernel(const short* __restrict__ QKV, short* __restrict__ P,
                           float* __restrict__ RS, int bbase)
{
    __shared__ __align__(16) short As[128 * 32];
    __shared__ __align__(16) short Bs[128 * 32];

    const int bid = blockIdx.x;
    const int bb = bid >> 10;
    const int r = bid & 1023;
    const int b = bbase + bb;
    const int m0 = 128 * (r >> 5);
    const int n0 = 128 * (r & 31);

    const short* Qb = QKV + (size_t)b * SDIM * DDIM;
    const short* Kb = QKV + (size_t)MROWS * DDIM + (size_t)b * SDIM * DDIM;

    const float4_t z4 = {0.f, 0.f, 0.f, 0.f};
    float4_t acc[4][4];
#pragma unroll
    for (int i = 0; i < 4; ++i)
#pragma unroll
        for (int j = 0; j < 4; ++j) acc[i][j] = z4;

    gemm_core(Qb, DDIM, Kb, DDIM, m0, n0, 16, As, Bs, acc);

    const int tid = threadIdx.x;
    const int w = tid >> 6, lane = tid & 63, quad = lane >> 4, l16 = lane & 15;
    const int wm = w >> 1, wn = w & 1;
    const float kSc = 1.44269504088896341f * 0.04419417382415922f;  // log2(e)/sqrt(512)
    short* Pb = P + (size_t)bb * SDIM * SDIM;
#pragma unroll
    for (int mt = 0; mt < 4; ++mt)
#pragma unroll
        for (int rr = 0; rr < 4; ++rr) {
            const int q = m0 + 64 * wm + 16 * mt + 4 * quad + rr;
            float sum = 0.f;
#pragma unroll
            for (int nt = 0; nt < 4; ++nt) {
                const float p = exp2f(acc[mt][nt][rr] * kSc);
                const short pb = f2bf(p);
                sum += bf2f(pb);
                Pb[(size_t)q * SDIM + n0 + 64 * wn + 16 * nt + l16] = pb;
            }
            sum += __shfl_xor(sum, 1); sum += __shfl_xor(sum, 2);
            sum += __shfl_xor(sum, 4); sum += __shfl_xor(sum, 8);
            if (l16 == 0) atomicAdd(&RS[(size_t)b * SDIM + q], sum);
        }
}

// ---------------- pv: out = (P @ Vt-rows) / RS ----------------
__global__ void pv_kernel(const short* __restrict__ P, const short* __restrict__ QKV,
                          const float* __restrict__ RS, void* __restrict__ out,
                          const int* __restrict__ flagp, int bbase)
{
    __shared__ __align__(16) short As[128 * 32];
    __shared__ __align__(16) short Bs[128 * 32];

    const int bf16out = *flagp;
    const int bid = blockIdx.x;
    const int bb = bid >> 7;
    const int r = bid & 127;
    const int b = bbase + bb;
    const int m0 = 128 * (r >> 2);
    const int n0 = 128 * (r & 3);

    const short* Pb = P + (size_t)bb * SDIM * SDIM;
    const short* Vt = QKV + 2 * (size_t)MROWS * DDIM + (size_t)b * SDIM;  // rows stride MROWS

    const float4_t z4 = {0.f, 0.f, 0.f, 0.f};
    float4_t acc[4][4];
#pragma unroll
    for (int i = 0; i < 4; ++i)
#pragma unroll
        for (int j = 0; j < 4; ++j) acc[i][j] = z4;

    gemm_core(Pb, SDIM, Vt, MROWS, m0, n0, 128, As, Bs, acc);

    const int tid = threadIdx.x;
    const int w = tid >> 6, lane = tid & 63, quad = lane >> 4, l16 = lane & 15;
    const int wm = w >> 1, wn = w & 1;
#pragma unroll
    for (int mt = 0; mt < 4; ++mt)
#pragma unroll
        for (int rr = 0; rr < 4; ++rr) {
            const size_t grow = (size_t)b * SDIM + m0 + 64 * wm + 16 * mt + 4 * quad + rr;
            const float inv = 1.0f / RS[grow];
#pragma unroll
            for (int nt = 0; nt < 4; ++nt) {
                const int n = n0 + 64 * wn + 16 * nt + l16;
                const float o = acc[mt][nt][rr] * inv;
                if (bf16out) ((short*)out)[grow * DDIM + n] = f2bf(o);
                else         ((float*)out)[grow * DDIM + n] = o;
            }
        }
}

// ---------------- Fallbacks (proven round-6/8 versions) ----------------
__global__ void proj_mfma_legacy(const void* __restrict__ X, const void* __restrict__ W1,
                          const void* __restrict__ W2, const void* __restrict__ W3,
                          short* __restrict__ QKV, const int* __restrict__ flagp)
{
    __shared__ __align__(16) short As[128][40];
    __shared__ __align__(16) short Bs[128][40];

    const int bf16in = *flagp;
    const int bid = blockIdx.x;
    const int g = bid >> 9;
    const int r = bid & 511;

    const void* Ap; const void* Bp; short* Op;
    int m0, n0, ldo;
    if (g == 2) {
        Ap = W3; Bp = X; Op = QKV + 2 * (size_t)MROWS * DDIM;
        m0 = 128 * (r & 3); n0 = 128 * (r >> 2); ldo = MROWS;
    } else {
        Ap = X; Bp = (g == 0) ? W1 : W2; Op = QKV + (size_t)g * MROWS * DDIM;
        m0 = 128 * (r >> 2); n0 = 128 * (r & 3); ldo = DDIM;
    }

    const float* Af = (const float*)Ap;  const float* Bf = (const float*)Bp;
    const short* Ah = (const short*)Ap;  const short* Bh = (const short*)Bp;

    const int tid = threadIdx.x;
    const int w = tid >> 6, lane = tid & 63, quad = lane >> 4, l16 = lane & 15;
    const int wm = w >> 1, wn = w & 1;
    const int rgrp = tid >> 3, cg = tid & 7;

    const float4_t z4 = {0.f, 0.f, 0.f, 0.f};
    float4_t acc[4][4];
#pragma unroll
    for (int i = 0; i < 4; ++i)
#pragma unroll
        for (int j = 0; j < 4; ++j) acc[i][j] = z4;

    for (int kk = 0; kk < 16; ++kk) {
        const int k0 = 32 * kk;
        __syncthreads();
        if (bf16in) {
#pragma unroll
            for (int i = 0; i < 4; ++i) {
                const int row = rgrp + 32 * i;
                *(short4_t*)&As[row][4 * cg] =
                    *(const short4_t*)(Ah + (size_t)(m0 + row) * DDIM + k0 + 4 * cg);
                *(short4_t*)&Bs[row][4 * cg] =
                    *(const short4_t*)(Bh + (size_t)(n0 + row) * DDIM + k0 + 4 * cg);
            }
        } else {
#pragma unroll
            for (int i = 0; i < 4; ++i) {
                const int row = rgrp + 32 * i;
                float4 va = *(const float4*)(Af + (size_t)(m0 + row) * DDIM + k0 + 4 * cg);
                short4_t sa = { f2bf(va.x), f2bf(va.y), f2bf(va.z), f2bf(va.w) };
                *(short4_t*)&As[row][4 * cg] = sa;
                float4 vb = *(const float4*)(Bf + (size_t)(n0 + row) * DDIM + k0 + 4 * cg);
                short4_t sb = { f2bf(vb.x), f2bf(vb.y), f2bf(vb.z), f2bf(vb.w) };
                *(short4_t*)&Bs[row][4 * cg] = sb;
            }
        }
        __syncthreads();

        short8_t af[4], bfr[4];
#pragma unroll
        for (int mt = 0; mt < 4; ++mt)
            af[mt] = *(const short8_t*)&As[64 * wm + 16 * mt + l16][8 * quad];
#pragma unroll
        for (int nt = 0; nt < 4; ++nt)
            bfr[nt] = *(const short8_t*)&Bs[64 * wn + 16 * nt + l16][8 * quad];
#pragma unroll
        for (int mt = 0; mt < 4; ++mt)
#pragma unroll
            for (int nt = 0; nt < 4; ++nt)
                acc[mt][nt] = __builtin_amdgcn_mfma_f32_16x16x32_bf16(af[mt], bfr[nt], acc[mt][nt], 0, 0, 0);
    }

#pragma unroll
    for (int mt = 0; mt < 4; ++mt)
#pragma unroll
        for (int nt = 0; nt < 4; ++nt)
#pragma unroll
            for (int rr = 0; rr < 4; ++rr) {
                const int m = m0 + 64 * wm + 16 * mt + 4 * quad + rr;
                const int n = n0 + 64 * wn + 16 * nt + l16;
                Op[(size_t)m * ldo + n] = f2bf(acc[mt][nt][rr]);
            }
}

__global__ void attn_mfma(const short* __restrict__ QKV, void* __restrict__ out,
                          const int* __restrict__ flagp)
{
    __shared__ __align__(16) short Ks[32][520];
    __shared__ __align__(16) short Ps[32][72];
    __shared__ float rowsum[2][32];

    const int bf16out = *flagp;
    const short* Qb = QKV;
    const short* Kb = QKV + (size_t)MROWS * DDIM;
    const short* Vt = QKV + 2 * (size_t)MROWS * DDIM;

    const int b = blockIdx.x >> 7;
    const int q0 = (blockIdx.x & 127) * 32;
    const int tid = threadIdx.x;
    const int w = tid >> 6, lane = tid & 63, quad = lane >> 4, l16 = lane & 15;
    const int strip = w >> 1, half = w & 1;

    short8_t qf[16];
    {
        const short* qrow = Qb + (size_t)(b * SDIM + q0 + 16 * strip + l16) * DDIM + 8 * quad;
#pragma unroll
        for (int kc = 0; kc < 16; ++kc)
            qf[kc] = *(const short8_t*)(qrow + 32 * kc);
    }

    const float4_t z4 = {0.f, 0.f, 0.f, 0.f};
    float4_t o[2][8];
#pragma unroll
    for (int mt = 0; mt < 2; ++mt)
#pragma unroll
        for (int nt = 0; nt < 8; ++nt) o[mt][nt] = z4;
    float rs[4] = {0.f, 0.f, 0.f, 0.f};

    const float kSc = 1.44269504088896341f * 0.04419417382415922f;

    for (int kt = 0; kt < 128; ++kt) {
        const int kv0 = 32 * kt;
        __syncthreads();
#pragma unroll
        for (int r = 0; r < 8; ++r) {
            const int kv = 8 * w + r;
            short8_t t = *(const short8_t*)(Kb + (size_t)(b * SDIM + kv0 + kv) * DDIM + 8 * lane);
            *(short8_t*)&Ks[kv][8 * lane] = t;
        }
        __syncthreads();

        float4_t sacc = z4;
#pragma unroll
        for (int kc = 0; kc < 16; ++kc) {
            short8_t kf = *(const short8_t*)&Ks[16 * half + l16][32 * kc + 8 * quad];
            sacc = __builtin_amdgcn_mfma_f32_16x16x32_bf16(qf[kc], kf, sacc, 0, 0, 0);
        }

#pragma unroll
        for (int r = 0; r < 4; ++r) {
            const float p = exp2f(sacc[r] * kSc);
            const short pb = f2bf(p);
            rs[r] += bf2f(pb);
            Ps[16 * strip + 4 * quad + r][16 * half + l16] = pb;
        }
        __syncthreads();

        short8_t pa0 = *(const short8_t*)&Ps[l16][8 * quad];
        short8_t pa1 = *(const short8_t*)&Ps[16 + l16][8 * quad];
#pragma unroll
        for (int nt = 0; nt < 8; ++nt) {
            const short* vp = Vt + (size_t)(128 * w + 16 * nt + l16) * MROWS
                            + (b * SDIM + kv0 + 8 * quad);
            short8_t vb = *(const short8_t*)vp;
            o[0][nt] = __builtin_amdgcn_mfma_f32_16x16x32_bf16(pa0, vb, o[0][nt], 0, 0, 0);
            o[1][nt] = __builtin_amdgcn_mfma_f32_16x16x32_bf16(pa1, vb, o[1][nt], 0, 0, 0);
        }
    }

#pragma unroll
    for (int r = 0; r < 4; ++r) {
        float v = rs[r];
        v += __shfl_xor(v, 1); v += __shfl_xor(v, 2);
        v += __shfl_xor(v, 4); v += __shfl_xor(v, 8);
        rs[r] = v;
    }
    if (l16 == 0) {
#pragma unroll
        for (int r = 0; r < 4; ++r)
            rowsum[half][16 * strip + 4 * quad + r] = rs[r];
    }
    __syncthreads();

#pragma unroll
    for (int mt = 0; mt < 2; ++mt)
#pragma unroll
        for (int r = 0; r < 4; ++r) {
            const int q = 16 * mt + 4 * quad + r;
            const float inv = 1.0f / (rowsum[0][q] + rowsum[1][q]);
            const size_t base = (size_t)(b * SDIM + q0 + q) * DDIM + 128 * w + l16;
            if (bf16out) {
                short* orow = (short*)out + base;
#pragma unroll
                for (int nt = 0; nt < 8; ++nt)
                    orow[16 * nt] = f2bf(o[mt][nt][r] * inv);
            } else {
                float* orow = (float*)out + base;
#pragma unroll
                for (int nt = 0; nt < 8; ++nt)
                    orow[16 * nt] = o[mt][nt][r] * inv;
            }
        }
}

__global__ void zero_out_kernel(short* __restrict__ out, int n) {
    int i = blockIdx.x * 256 + threadIdx.x;
    if (i < n) out[i] = 0;
}

extern "C" void kernel_launch(void* const* d_in, const int* in_sizes, int n_in,
                              void* d_out, int out_size, void* d_ws, size_t ws_size,
                              hipStream_t stream) {
    const void* token = d_in[0];
    const void* Wp[3] = { d_in[1], d_in[2], d_in[3] };
    {
        int wi = 0;
        const void* tk = nullptr; const void* ws3[3] = {nullptr, nullptr, nullptr};
        bool ok = true;
        for (int i = 0; i < n_in && i < 4; ++i) {
            if (in_sizes[i] == BDIM * SDIM * DDIM) { if (tk) ok = false; tk = d_in[i]; }
            else if (in_sizes[i] == DDIM * DDIM) { if (wi < 3) ws3[wi++] = d_in[i]; else ok = false; }
            else ok = false;
        }
        if (ok && tk && wi == 3) { token = tk; Wp[0] = ws3[0]; Wp[1] = ws3[1]; Wp[2] = ws3[2]; }
    }

    const size_t qkvBytes = 3 * (size_t)MROWS * DDIM * sizeof(short);  // 48 MB
    const size_t need_base = qkvBytes + 256;
    if (ws_size < need_base) {
        zero_out_kernel<<<(out_size + 255) / 256, 256, 0, stream>>>((short*)d_out, out_size);
        return;
    }

    short* QKV = (short*)d_ws;
    int* flag = (int*)((char*)d_ws + qkvBytes);
    short* P = (short*)((char*)d_ws + need_base);   // P slab; Xb/Wb overlap (dead before qkt)
    const size_t pElems1 = (size_t)SDIM * SDIM;

    int nb = 0;
    for (int cand = 4; cand >= 1; cand >>= 1) {
        const size_t need = need_base + (size_t)cand * pElems1 * sizeof(short)
                          + (size_t)MROWS * sizeof(float);
        if (ws_size >= need) { nb = cand; break; }
    }

    detect_kernel<<<1, 256, 0, stream>>>((const uint32_t*)token, flag);

    if (nb == 0) {
        proj_mfma_legacy<<<dim3(1536), 256, 0, stream>>>(token, Wp[0], Wp[1], Wp[2], QKV, flag);
        attn_mfma<<<dim3(512), 256, 0, stream>>>(QKV, d_out, flag);
        return;
    }

    // Xb|W1b|W2b|W3b live at the head of the P slab (18.35 MB <= 32 MB min slab).
    short* XbWb = P;
    const size_t cvt4 = (XB_ELEMS + 3 * W_ELEMS) / 4;  // 2293760 lanes
    convert_kernel<<<dim3((unsigned)(cvt4 / 256)), 256, 0, stream>>>(
        token, Wp[0], Wp[1], Wp[2], XbWb, flag);
    proj_fast<<<dim3(1536), 256, 0, stream>>>(XbWb, QKV);

    float* RS = (float*)(P + (size_t)nb * pElems1);
    zero_rs_kernel<<<dim3(MROWS / 256), 256, 0, stream>>>(RS);
    for (int p = 0; p < BDIM / nb; ++p) {
        const int bbase = p * nb;
        qkt_kernel<<<dim3(nb * 1024), 256, 0, stream>>>(QKV, P, RS, bbase);
        pv_kernel<<<dim3(nb * 128), 256, 0, stream>>>(P, QKV, RS, d_out, flag, bbase);
    }
}